// Round 6
// baseline (108.854 us; speedup 1.0000x reference)
//
#include <hip/hip_runtime.h>
#include <math.h>

// QuanvolutionPlus round 10: NSAMP=10 task-remap — kill the 23% slot waste.
//
// Session evidence: memory-path (r8), MFMA offload (r6), occupancy experiments
// all land in the +-2.5us noise band; ONLY total VALU instruction count moves
// the total (r9 packed pairs: -2.6us for ~35% feature-instr cut). Remaining
// cut: the 32-lane pair mapping wastes 23.4% of feature iters (ceil(98/32)=4
// for 3.06 of content; h=3 is nearly all clamped dead work).
//
// Round 10:
//  - 10 samples/block, block-level task remap: task g = tid + 256h (h=0..3),
//    valid g < 980; s = g/98 (compiler magic-mul), pp = g%98; pair =
//    (pp, pp+98) — BOTH always in [0,195]: patch clamp deleted. Waste 4.3%.
//    Grid 2048 -> 1639 blocks: -20% wave-iterations, +~10 ops/iter remap.
//  - LDS 2x10x808x2 = 32320B -> 5 blocks/CU = 20 waves/CU (launch_bounds
//    (256,5), VGPR cap 102 >= ~75 est).
//  - packed-f32 (v_pk_fma_f32) conv+quantum body: verbatim round 9 (passed).
//  - MFMA matvec 16x16x32 f16: A rows 0..9 of 16 valid (rest zeros), K=800,
//    7/7/7/4 wave split; full-wave D store to pw[4][16][16] (4KB, aliases
//    clsB); 160-thread 16-lane-group softmax. Layouts pass-verified r5-r9.
//
// Index facts (verified rounds 1-9): cls flat n = c*196+p ; q flat n = 4p+k ;
// logits[o] = sum_n fused[n]*lin_w[o*784+n] + lin_b[o]. MFMA 16x16x32 f16:
// A row=lane&15, k=(lane>>4)*8+j ; B col=lane&15, same k ; D col=lane&15,
// row=(lane>>4)*4+reg.

typedef __fp16 h2 __attribute__((ext_vector_type(2)));
typedef __fp16 h4 __attribute__((ext_vector_type(4)));
typedef __fp16 h8 __attribute__((ext_vector_type(8)));
typedef float  f2 __attribute__((ext_vector_type(2)));
typedef float  f32x4 __attribute__((ext_vector_type(4)));

#define NSAMP 10
#define FSTRIDE 808   // f16 elems/row: 784 data + 16 zeroed pad (k=784..799) + 8 slack

__device__ __forceinline__ float rfl(float v) {
    return __int_as_float(__builtin_amdgcn_readfirstlane(__float_as_int(v)));
}

__device__ __forceinline__ f2 max0(f2 v) {
    f2 r; r.x = fmaxf(v.x, 0.f); r.y = fmaxf(v.y, 0.f); return r;
}

// round-6/9 verified patch gather (global float2, clamp+mask halo), pre-masked
__device__ __forceinline__ void load_patch(const float* __restrict__ xs, int p,
                                           float a[9]) {
    unsigned ii = (unsigned)p / 14u;
    int j  = p - (int)ii * 14;
    int rm = (int)ii * 56 + 2 * j;              // float index of x[2i][2j]
    float2 Rm = *(const float2*)(xs + rm);      // a11 a12
    float2 Rb = *(const float2*)(xs + rm + 28); // a21 a22
    int rt = rm - 28;  rt  = (rt  > 0) ? rt  : 0;
    float2 Rt = *(const float2*)(xs + rt);      // a01 a02
    int olt = rm - 30; olt = (olt > 0) ? olt : 0;
    float2 Lt = *(const float2*)(xs + olt);     // .y = a00
    int olm = rm - 2;  olm = (olm > 0) ? olm : 0;
    float2 Lm = *(const float2*)(xs + olm);     // .y = a10
    float2 Lb = *(const float2*)(xs + olm + 28);// .y = a20
    float mt = (ii > 0u) ? 1.f : 0.f;
    float ml = (j  > 0 ) ? 1.f : 0.f;
    a[0] = Lt.y * (mt * ml); a[1] = Rt.x * mt; a[2] = Rt.y * mt;
    a[3] = Lm.y * ml;        a[4] = Rm.x;      a[5] = Rm.y;
    a[6] = Lb.y * ml;        a[7] = Rb.x;      a[8] = Rb.y;
}

__global__ __launch_bounds__(256, 5)
void quanv_fused(const float* __restrict__ x,
                 const float* __restrict__ conv_w,
                 const float* __restrict__ bn_gamma,
                 const float* __restrict__ bn_beta,
                 const float* __restrict__ bn_mean,
                 const float* __restrict__ bn_var,
                 const float* __restrict__ var_params,
                 const float* __restrict__ lin_w,
                 const float* __restrict__ lin_b,
                 float* __restrict__ out, int B)
{
    __shared__ __align__(16) __fp16 clsB[NSAMP * FSTRIDE]; // pw aliases this later
    __shared__ __align__(16) __fp16 qB[NSAMP * FSTRIDE];

    const int tid  = threadIdx.x;
    const int lane = tid & 63;
    const int wave = tid >> 6;

    // pad k=784..799 of both buffers (A operand must be clean where B is zero)
    if (tid < NSAMP * 16) {
        int r = tid >> 4, buf = (tid >> 3) & 1, w = tid & 7;
        int* wp = (int*)((buf ? qB : clsB) + r * FSTRIDE + 784);
        wp[w] = 0;
    }

    // ---- uniform small params (SGPR via readfirstlane) ----
    float inv[4], addc[4];
    #pragma unroll
    for (int c = 0; c < 4; ++c) {
        float iv = bn_gamma[c] * rsqrtf(bn_var[c] + 1e-5f);
        inv[c]  = rfl(iv);
        addc[c] = rfl(bn_beta[c] - bn_mean[c] * iv);
    }
    float cv[4], sv[4];
    #pragma unroll
    for (int k = 0; k < 4; ++k) {
        float s, c;
        __sincosf(var_params[k] * 0.5f, &s, &c);
        sv[k] = rfl(s); cv[k] = rfl(c);
    }

    // ---- feature phase: block-level pair-task remap, 4 packed hyper-iters ----
    // task g -> sample s = g/98, pair (pp, pp+98), pp = g%98. 980 tasks.
    const int sbase = blockIdx.x * NSAMP;

    #pragma unroll
    for (int h = 0; h < 4; ++h) {
        const int g  = tid + 256 * h;
        const bool act = (g < NSAMP * 98);
        const int gc = act ? g : (NSAMP * 98 - 1);
        const int s_loc = (int)((unsigned)gc / 98u);
        const int pp    = gc - 98 * s_loc;

        const int sg  = sbase + s_loc;
        const int sgc = (sg < B) ? sg : (B - 1);
        const float* xs = x + (size_t)sgc * 784;

        float A[9], Bv[9];
        load_patch(xs, pp, A);         // pp in [0,97]
        load_patch(xs, pp + 98, Bv);   // pp+98 in [98,195] — always valid
        f2 aP[9];
        #pragma unroll
        for (int k2 = 0; k2 < 9; ++k2) { f2 t = {A[k2], Bv[k2]}; aP[k2] = t; }

        // conv + BN + ReLU, packed over the pair (weights splat from SGPR)
        f2 hc[4];
        #pragma unroll
        for (int c = 0; c < 4; ++c) {
            f2 hx = aP[0] * conv_w[c*9+0];
            hx += aP[1] * conv_w[c*9+1];
            hx += aP[2] * conv_w[c*9+2];
            hx += aP[3] * conv_w[c*9+3];
            hx += aP[4] * conv_w[c*9+4];
            hx += aP[5] * conv_w[c*9+5];
            hx += aP[6] * conv_w[c*9+6];
            hx += aP[7] * conv_w[c*9+7];
            hx += aP[8] * conv_w[c*9+8];
            hc[c] = max0(hx * inv[c] + addc[c]);
        }

        // quantum chain, packed over the pair (verbatim r9, pass-verified)
        f2 haP = 0.5f * (aP[4] + aP[7]);   // a11 + a21
        f2 hbP = 0.5f * (aP[5] + aP[8]);   // a12 + a22
        float s0x, c0x, s0y, c0y, s1x, c1x, s1y, c1y;
        __sincosf(haP.x, &s0x, &c0x); __sincosf(haP.y, &s0y, &c0y);
        __sincosf(hbP.x, &s1x, &c1x); __sincosf(hbP.y, &s1y, &c1y);
        f2 c0 = {c0x, c0y}, s0 = {s0x, s0y};
        f2 c1 = {c1x, c1y}, s1 = {s1x, s1y};
        f2 m00 = c0*c1, m01 = c0*s1;
        f2 m10 = s0*s1, m11 = s0*c1;                                 // enc + CNOT(0->1)
        f2 t00 = cv[0]*m00 - sv[0]*m10, t01 = cv[0]*m01 - sv[0]*m11;
        f2 t10 = sv[0]*m00 + cv[0]*m10, t11 = sv[0]*m01 + cv[0]*m11; // RY(v0) w0
        f2 u00 = cv[1]*t00 - sv[1]*t01, u01 = sv[1]*t00 + cv[1]*t01;
        f2 u10 = cv[1]*t10 - sv[1]*t11, u11 = sv[1]*t10 + cv[1]*t11; // RY(v1) w1
        f2 w01 = u11, w11 = u01;                                      // CNOT(1->0)
        f2 p00 = cv[2]*u00 - sv[2]*u10, p01 = cv[2]*w01 - sv[2]*w11;
        f2 p10 = sv[2]*u00 + cv[2]*u10, p11 = sv[2]*w01 + cv[2]*w11; // RY(v2) w0
        f2 q00 = cv[3]*p00 - sv[3]*p01, q01 = sv[3]*p00 + cv[3]*p01;
        f2 q10 = cv[3]*p10 - sv[3]*p11, q11 = sv[3]*p10 + cv[3]*p11; // RY(v3) w1

        f2 z0 = q00*q00 + q01*q01 - q10*q10 - q11*q11;
        f2 z1 = q00*q00 + q10*q10 - q01*q01 - q11*q11;
        f2 x0 = 2.f * (q00*q10 + q01*q11);
        f2 x1 = 2.f * (q00*q01 + q10*q11);

        if (act) {
            __fp16* clsRow = clsB + s_loc * FSTRIDE;
            __fp16* qRow   = qB   + s_loc * FSTRIDE;
            // patch pp (x lanes of the pair)
            {
                h2 ca = __builtin_amdgcn_cvt_pkrtz(hc[0].x, hc[1].x);
                h2 cb = __builtin_amdgcn_cvt_pkrtz(hc[2].x, hc[3].x);
                __fp16* cr = clsRow + pp;                  // n = c*196+p
                cr[0] = ca.x; cr[196] = ca.y; cr[392] = cb.x; cr[588] = cb.y;
                h2 zz = __builtin_amdgcn_cvt_pkrtz(z0.x, z1.x);
                h2 xx = __builtin_amdgcn_cvt_pkrtz(x0.x, x1.x);
                h4 qv = {zz.x, zz.y, xx.x, xx.y};
                *(h4*)(qRow + 4 * pp) = qv;                // n = 4p+k
            }
            // patch pp+98 (y lanes of the pair)
            {
                h2 ca = __builtin_amdgcn_cvt_pkrtz(hc[0].y, hc[1].y);
                h2 cb = __builtin_amdgcn_cvt_pkrtz(hc[2].y, hc[3].y);
                __fp16* cr = clsRow + pp + 98;
                cr[0] = ca.x; cr[196] = ca.y; cr[392] = cb.x; cr[588] = cb.y;
                h2 zz = __builtin_amdgcn_cvt_pkrtz(z0.y, z1.y);
                h2 xx = __builtin_amdgcn_cvt_pkrtz(x0.y, x1.y);
                h4 qv = {zz.x, zz.y, xx.x, xx.y};
                *(h4*)(qRow + 4 * (pp + 98)) = qv;
            }
        }
    }

    // ---- B fragments (lin_w -> f16) to registers, AFTER the hot loop ----
    const int bcol = lane & 15, bkg = lane >> 4;
    const __fp16 hz = (__fp16)0.f;
    const h8 hz8 = {hz, hz, hz, hz, hz, hz, hz, hz};
    h8 bfrag[7];
    #pragma unroll
    for (int t = 0; t < 7; ++t) {
        int st = wave * 7 + t;
        int kb = st * 32 + bkg * 8;
        h8 bf = hz8;
        if (bcol < 10 && kb < 784) {
            const float4* lw4 = (const float4*)(lin_w + bcol * 784 + kb);
            float4 v0 = lw4[0], v1 = lw4[1];
            h2 p0 = __builtin_amdgcn_cvt_pkrtz(v0.x, v0.y);
            h2 p1 = __builtin_amdgcn_cvt_pkrtz(v0.z, v0.w);
            h2 p2 = __builtin_amdgcn_cvt_pkrtz(v1.x, v1.y);
            h2 p3 = __builtin_amdgcn_cvt_pkrtz(v1.z, v1.w);
            h8 tv = {p0.x, p0.y, p1.x, p1.y, p2.x, p2.y, p3.x, p3.y};
            bf = tv;
        }
        bfrag[t] = bf;
    }

    __syncthreads();   // (1) features + pad zeros visible to all waves

    // ---- MFMA matvec: wave w owns K-steps 7w..7w+6 (st<25 valid) ----
    f32x4 acc = {0.f, 0.f, 0.f, 0.f};
    {
        const int arow = lane & 15, akg = lane >> 4;
        #pragma unroll
        for (int t = 0; t < 7; ++t) {
            int st = wave * 7 + t;
            if (st < 25) {   // wave-uniform branch
                h8 a = hz8;
                if (arow < NSAMP) {   // rows 10-15 feed zeros
                    int off = arow * FSTRIDE + st * 32 + akg * 8;
                    a = *(const h8*)(clsB + off) + *(const h8*)(qB + off); // fused add
                }
                acc = __builtin_amdgcn_mfma_f32_16x16x32_f16(a, bfrag[t], acc, 0, 0, 0);
            }
        }
    }

    __syncthreads();   // (2) all cls reads done -> safe to alias partials onto clsB
    float* pw = (float*)clsB;   // [4 waves][16 rows][16 cols] = 4KB
    {
        const int col = lane & 15, rb = (lane >> 4) * 4;  // full-wave D store
        #pragma unroll
        for (int r = 0; r < 4; ++r)
            pw[(wave * 16 + rb + r) * 16 + col] = acc[r];
    }
    __syncthreads();   // (3) partials visible

    // ---- cross-wave sum + per-sample softmax (16 lanes per sample) ----
    if (tid < NSAMP * 16) {
        const int c  = tid & 15;   // class
        const int sl = tid >> 4;   // sample in block (0..9)
        float L = pw[sl * 16 + c] + pw[(16 + sl) * 16 + c]
                + pw[(32 + sl) * 16 + c] + pw[(48 + sl) * 16 + c];
        L = (c < 10) ? (L + lin_b[c]) : -1e30f;
        float mx = L;
        mx = fmaxf(mx, __shfl_xor(mx, 1, 16));
        mx = fmaxf(mx, __shfl_xor(mx, 2, 16));
        mx = fmaxf(mx, __shfl_xor(mx, 4, 16));
        mx = fmaxf(mx, __shfl_xor(mx, 8, 16));
        float se = (c < 10) ? __expf(L - mx) : 0.f;
        se += __shfl_xor(se, 1, 16);
        se += __shfl_xor(se, 2, 16);
        se += __shfl_xor(se, 4, 16);
        se += __shfl_xor(se, 8, 16);
        const int sg2 = blockIdx.x * NSAMP + sl;
        if (c < 10 && sg2 < B)
            out[(size_t)sg2 * 10 + c] = L - mx - __logf(se);
    }
}

extern "C" void kernel_launch(void* const* d_in, const int* in_sizes, int n_in,
                              void* d_out, int out_size, void* d_ws, size_t ws_size,
                              hipStream_t stream) {
    const float* x          = (const float*)d_in[0];
    const float* conv_w     = (const float*)d_in[1];
    const float* bn_gamma   = (const float*)d_in[2];
    const float* bn_beta    = (const float*)d_in[3];
    const float* bn_mean    = (const float*)d_in[4];
    const float* bn_var     = (const float*)d_in[5];
    const float* var_params = (const float*)d_in[6];
    const float* lin_w      = (const float*)d_in[7];
    const float* lin_b      = (const float*)d_in[8];
    float* out = (float*)d_out;

    const int B = in_sizes[0] / 784;
    const int blocks = (B + NSAMP - 1) / NSAMP;
    quanv_fused<<<blocks, 256, 0, stream>>>(x, conv_w, bn_gamma, bn_beta, bn_mean,
                                            bn_var, var_params, lin_w, lin_b, out, B);
}